// Round 2
// baseline (1084.583 us; speedup 1.0000x reference)
//
#include <hip/hip_runtime.h>
#include <hip/hip_bf16.h>

// ---------------------------------------------------------------------------
// Fused 3-layer GRU (B*N=16384 seqs, T=20, HS=128) for MI355X / gfx950.
// R15: 8-wave layer-wavefront (512 thr, 2 waves/SIMD -> 256 VGPR/wave budget)
// with NAMED-VARIABLE weight register cache (24 half8 = 96 VGPR/wave):
//   waves 0-3: layer 0, 2 ctiles each (+ fused embedding, tid<256 unchanged);
//              cache = gh ks0-1 (12 frags) + ALL of Wih0 (12 frags, K=64)
//              -> streams only gh ks2-3 = 12 KB/phase.
//   waves 4-7: layers 1-2, 4 ctiles each; cache = gh ks0-1 (24 frags)
//              -> streams gh ks2-3 + gi (72 KB/phase).
// Per-block per-phase weight L2 volume: 528 KB -> 336 KB (0.64x).
// R14 post-mortem: array cache was demoted to scratch (FETCH 674 MB == the
// predicted scratch-reload volume; rule #20 + unified-file AGPR accounting
// leaves only ~22 free regs at 3 waves/SIMD). Hence: 2 waves/SIMD + named
// vars. Canary: FETCH_SIZE must stay ~14 MB; >=50 MB means demotion/spill.
// ---------------------------------------------------------------------------

typedef _Float16 half8 __attribute__((ext_vector_type(8)));
typedef _Float16 half4 __attribute__((ext_vector_type(4)));
typedef float floatx4 __attribute__((ext_vector_type(4)));

#define MFMA16(a, b, c) __builtin_amdgcn_mfma_f32_16x16x32_f16((a), (b), (c), 0, 0, 0)

static __device__ __forceinline__ float ldin(const void* p, long i, bool f32) {
    return f32 ? ((const float*)p)[i]
               : __bfloat162float(((const __hip_bfloat16*)p)[i]);
}

static __device__ __forceinline__ bool detect_f32(const void* peT, const void* x) {
    const __hip_bfloat16* a = (const __hip_bfloat16*)peT;
    const __hip_bfloat16* b = (const __hip_bfloat16*)x;
    bool weird = false;
    for (int i = 0; i < 20; i++) {
        float v = fabsf(__bfloat162float(a[i]));
        if (!(v == 0.0f || (v > 1e-8f && v < 1e8f))) weird = true;
    }
    for (int i = 0; i < 64; i++) {
        float v = fabsf(__bfloat162float(b[i]));
        if (!(v == 0.0f || (v > 1e-8f && v < 1e8f))) weird = true;
    }
    return weird;
}

// clampless: exp2(+inf)->inf, rcp(inf)->0 give correct saturation limits
static __device__ __forceinline__ float fsigm(float x) {
    float e = __builtin_amdgcn_exp2f(-1.442695041f * x);
    return __builtin_amdgcn_rcpf(1.0f + e);
}
static __device__ __forceinline__ float ftanh(float x) {
    float e = __builtin_amdgcn_exp2f(2.885390082f * x);  // exp(2x)
    return 1.0f - 2.0f * __builtin_amdgcn_rcpf(1.0f + e);
}

// ws fragment layout (each frag = 512 halfs = 64 lanes x 8): slot order
//   [0,288)   Whh   (3 layers x 96)   frag in layer: (ctile*3+g)*4+ks, ctile 0..7
//   [288,480) WihR  (2 layers x 96)   same formula
//   [480,528) Wih0  (48)              (ctile*3+g)*2+ks   (K=64)
//   [528,544) outW  (16)              otile*4+ks
__global__ __launch_bounds__(64) void prepack_kernel(
    const void* __restrict__ Whh,
    const void* __restrict__ WihR,
    const void* __restrict__ Wih0,
    const void* __restrict__ outW,
    const void* __restrict__ peT,
    const void* __restrict__ x,
    _Float16* __restrict__ ws)
{
    const bool f32 = detect_f32(peT, x);
    int fid  = blockIdx.x;
    int lane = threadIdx.x;
    int nlo = lane & 15, quad = lane >> 4;
    const void* src;
    long base;
    int row, k0, ldk;
    if (fid < 288) {
        int l = fid / 96, r = fid % 96;
        int ks = r & 3, q1 = r >> 2, g = q1 % 3, ctile = q1 / 3;
        row = g * 128 + ctile * 16 + nlo; k0 = ks * 32 + quad * 8; ldk = 128;
        src = Whh; base = (long)l * 384 * 128;
    } else if (fid < 480) {
        int f = fid - 288; int l = f / 96, r = f % 96;
        int ks = r & 3, q1 = r >> 2, g = q1 % 3, ctile = q1 / 3;
        row = g * 128 + ctile * 16 + nlo; k0 = ks * 32 + quad * 8; ldk = 128;
        src = WihR; base = (long)l * 384 * 128;
    } else if (fid < 528) {
        int r = fid - 480;
        int ks = r & 1, q1 = r >> 1, g = q1 % 3, ctile = q1 / 3;
        row = g * 128 + ctile * 16 + nlo; k0 = ks * 32 + quad * 8; ldk = 64;
        src = Wih0; base = 0;
    } else {
        int r = fid - 528; int ks = r & 3, ot = r >> 2;
        row = ot * 16 + nlo; k0 = ks * 32 + quad * 8; ldk = 128;
        src = outW; base = 0;
    }
    _Float16* d = ws + (long)fid * 512 + lane * 8;
#pragma unroll
    for (int j = 0; j < 8; j++)
        d[j] = (_Float16)ldin(src, base + (long)row * ldk + k0 + j, f32);
}

// ---- named-register weight cache machinery (rule #20: no arrays) ----------
#define CAT3(a, b, c) C##a##b##c
#define CN(a, b, c)   CAT3(a, b, c)

#define FOR6(M, CT)        M(CT,0,0) M(CT,0,1) M(CT,1,0) M(CT,1,1) M(CT,2,0) M(CT,2,1)
#define FOR6B(M, DCT, SCT) M(DCT,SCT,0,0) M(DCT,SCT,0,1) M(DCT,SCT,1,0) M(DCT,SCT,1,1) M(DCT,SCT,2,0) M(DCT,SCT,2,1)

#define MF4(WF, G) \
    acc[G][0] = MFMA16((WF), B0, acc[G][0]); \
    acc[G][1] = MFMA16((WF), B1, acc[G][1]); \
    acc[G][2] = MFMA16((WF), B2, acc[G][2]); \
    acc[G][3] = MFMA16((WF), B3, acc[G][3]);

// gh step, ks 0/1: weights from named cache
#define GH_C(CT, KS) { \
    half8 B0 = *(const half8*)&ghp[(0*16+nlo)*136 + (KS)*32 + qk]; \
    half8 B1 = *(const half8*)&ghp[(1*16+nlo)*136 + (KS)*32 + qk]; \
    half8 B2 = *(const half8*)&ghp[(2*16+nlo)*136 + (KS)*32 + qk]; \
    half8 B3 = *(const half8*)&ghp[(3*16+nlo)*136 + (KS)*32 + qk]; \
    MF4(CN(CT,0,KS), 0) MF4(CN(CT,1,KS), 1) MF4(CN(CT,2,KS), 3) }

// gh step, ks 2/3: weights streamed from L2
#define GH_S(KS) { \
    half8 B0 = *(const half8*)&ghp[(0*16+nlo)*136 + (KS)*32 + qk]; \
    half8 B1 = *(const half8*)&ghp[(1*16+nlo)*136 + (KS)*32 + qk]; \
    half8 B2 = *(const half8*)&ghp[(2*16+nlo)*136 + (KS)*32 + qk]; \
    half8 B3 = *(const half8*)&ghp[(3*16+nlo)*136 + (KS)*32 + qk]; \
    { half8 Wf = *(const half8*)(ws + ((long)(lb96 + (c8*3+0)*4 + (KS)))*512 + lane8); MF4(Wf, 0) } \
    { half8 Wf = *(const half8*)(ws + ((long)(lb96 + (c8*3+1)*4 + (KS)))*512 + lane8); MF4(Wf, 1) } \
    { half8 Wf = *(const half8*)(ws + ((long)(lb96 + (c8*3+2)*4 + (KS)))*512 + lane8); MF4(Wf, 3) } }

// gi step for layer 0: Wih0 fully cached (slots DCT = CT+2)
#define GI0_C(DCT, KS) { \
    half8 B0 = *(const half8*)&ep[(0*16+nlo)*72 + (KS)*32 + qk]; \
    half8 B1 = *(const half8*)&ep[(1*16+nlo)*72 + (KS)*32 + qk]; \
    half8 B2 = *(const half8*)&ep[(2*16+nlo)*72 + (KS)*32 + qk]; \
    half8 B3 = *(const half8*)&ep[(3*16+nlo)*72 + (KS)*32 + qk]; \
    MF4(CN(DCT,0,KS), 0) MF4(CN(DCT,1,KS), 1) MF4(CN(DCT,2,KS), 2) }

// gi step for layers 1-2: streamed
#define GI12_S(KS) { \
    half8 B0 = *(const half8*)&gp[(0*16+nlo)*136 + (KS)*32 + qk]; \
    half8 B1 = *(const half8*)&gp[(1*16+nlo)*136 + (KS)*32 + qk]; \
    half8 B2 = *(const half8*)&gp[(2*16+nlo)*136 + (KS)*32 + qk]; \
    half8 B3 = *(const half8*)&gp[(3*16+nlo)*136 + (KS)*32 + qk]; \
    { half8 Wf = *(const half8*)(ws + ((long)(gib + (c8*3+0)*4 + (KS)))*512 + lane8); MF4(Wf, 0) } \
    { half8 Wf = *(const half8*)(ws + ((long)(gib + (c8*3+1)*4 + (KS)))*512 + lane8); MF4(Wf, 1) } \
    { half8 Wf = *(const half8*)(ws + ((long)(gib + (c8*3+2)*4 + (KS)))*512 + lane8); MF4(Wf, 2) } }

#define ACC_INIT \
    floatx4 acc[4][4]; \
    _Pragma("unroll") for (int g = 0; g < 4; g++) { \
        floatx4 b = *(const floatx4*)&biasS[(l*4+g)*128 + c4]; \
        _Pragma("unroll") for (int rt = 0; rt < 4; rt++) acc[g][rt] = b; }

#define NONLIN \
    _Pragma("unroll 2") for (int rt = 0; rt < 4; rt++) { \
        half4 ho = *(const half4*)&hA[l][p][rt*16+nlo][c4]; \
        half4 hn; \
        _Pragma("unroll") for (int rg = 0; rg < 4; rg++) { \
            float r = fsigm(acc[0][rt][rg]); \
            float z = fsigm(acc[1][rt][rg]); \
            float n = ftanh(acc[2][rt][rg] + r * acc[3][rt][rg]); \
            hn[rg] = (_Float16)(n + z * ((float)ho[rg] - n)); } \
        *(half4*)&hA[l][q][rt*16+nlo][c4] = hn; }

#define L0CT(CT, DCT) { \
    const int c8 = W*2 + CT; const int c4 = c8*16 + quad*4; \
    ACC_INIT \
    GH_C(CT,0) GH_C(CT,1) GH_S(2) GH_S(3) \
    GI0_C(DCT,0) GI0_C(DCT,1) \
    NONLIN }

#define L12CT(CT) { \
    const int c8 = H4 + CT; const int c4 = c8*16 + quad*4; \
    ACC_INIT \
    GH_C(CT,0) GH_C(CT,1) GH_S(2) GH_S(3) \
    GI12_S(0) GI12_S(1) GI12_S(2) GI12_S(3) \
    NONLIN }

#define IL0GH(CT,G,KS) CN(CT,G,KS) = *(const half8*)(ws + ((long)((((W*2+CT)*3+G)*4)+(KS)))*512 + lane8);
#define IL0GI(DCT,SCT,G,KS) CN(DCT,G,KS) = *(const half8*)(ws + ((long)(480 + (((W*2+SCT)*3+G)*2)+(KS)))*512 + lane8);
#define IL12(CT,G,KS) CN(CT,G,KS) = *(const half8*)(ws + ((long)(l*96 + (((H4+CT)*3+G)*4)+(KS)))*512 + lane8);

__global__ __launch_bounds__(512, 2) void rnn_fused(
    const void* __restrict__ x,
    const void* __restrict__ peA,
    const void* __restrict__ peT,
    const void* __restrict__ embW,
    const void* __restrict__ embB,
    const void* __restrict__ bih,
    const void* __restrict__ bhh,
    const void* __restrict__ outB,
    const _Float16* __restrict__ ws,
    float* __restrict__ out)
{
    __shared__ __align__(16) _Float16 hA[3][2][64][136];
    __shared__ __align__(16) _Float16 eA[2][64][72];
    __shared__ float emb0[64], emb1[64], embb[64];
    __shared__ float biasS[1536];   // [l][R,Z,Ni,Nh][128]

    const bool f32 = detect_f32(peT, x);

    const int tid  = threadIdx.x;
    const int w    = tid >> 6;      // 0..7
    const int lane = tid & 63;
    const int nlo  = lane & 15;
    const int quad = lane >> 4;
    const int qk   = quad * 8;
    const int lane8 = lane * 8;
    const int m0   = blockIdx.x * 64;
    const int l    = (w < 4) ? 0 : ((w < 6) ? 1 : 2);
    const int W    = w & 3;         // l0 quarter: ctiles W*2, W*2+1
    const int H4   = (w & 1) * 4;   // l1/l2 half: ctiles H4..H4+3
    const int lb96 = l * 96;                  // Whh frag base for this layer
    const int gib  = 288 + (l - 1) * 96;      // WihR frag base (l>=1 only)

    for (int i = tid; i < 3 * 2 * 64 * 136; i += 512)
        (&hA[0][0][0][0])[i] = (_Float16)0.f;
    if (tid < 64) {
        emb0[tid] = ldin(embW, tid * 2 + 0, f32);
        emb1[tid] = ldin(embW, tid * 2 + 1, f32);
        embb[tid] = ldin(embB, tid, f32);
    }
    for (int idx = tid; idx < 1536; idx += 512) {
        int ll = idx >> 9, r = idx & 511, g = r >> 7, c = r & 127;
        float v;
        if      (g == 0) v = ldin(bih, ll * 384 + c, f32)       + ldin(bhh, ll * 384 + c, f32);
        else if (g == 1) v = ldin(bih, ll * 384 + 128 + c, f32) + ldin(bhh, ll * 384 + 128 + c, f32);
        else if (g == 2) v = ldin(bih, ll * 384 + 256 + c, f32);
        else             v = ldin(bhh, ll * 384 + 256 + c, f32);
        biasS[idx] = v;
    }

    // ---- persistent weight register cache: 24 NAMED half8 (96 VGPR) ----
    half8 C000, C001, C010, C011, C020, C021,
          C100, C101, C110, C111, C120, C121,
          C200, C201, C210, C211, C220, C221,
          C300, C301, C310, C311, C320, C321;
    if (l == 0) {
        // slots 0,1: gh ks0-1 for ctiles W*2, W*2+1; slots 2,3: all of Wih0
        FOR6(IL0GH, 0) FOR6(IL0GH, 1)
        FOR6B(IL0GI, 2, 0) FOR6B(IL0GI, 3, 1)
    } else {
        // slots 0..3: gh ks0-1 for ctiles H4..H4+3
        FOR6(IL12, 0) FOR6(IL12, 1) FOR6(IL12, 2) FOR6(IL12, 3)
    }

    const int em = tid >> 2;          // embedding seq (layer-0 waves: tid<256)
    const int ej = (tid & 3) * 16;    // embedding col base
    const float peAg = ldin(peA, ((m0 + em) & 7), f32);

    __syncthreads();

#pragma unroll 1
    for (int s = 0; s < 23; s++) {
        const int t = s - 1 - l;
        if (t >= 0 && t < 20) {
            const int p = (t + 1) & 1;
            const int q = t & 1;
            const _Float16* ghp = &hA[l][p][0][0];
            if (l == 0) {
                const _Float16* ep = &eA[t & 1][0][0];
                L0CT(0, 2) L0CT(1, 3)
            } else {
                const _Float16* gp = &hA[l - 1][t & 1][0][0];
                L12CT(0) L12CT(1) L12CT(2) L12CT(3)
            }
        }
        // ---- embedding fused into layer-0 waves: e(t=s) -> eA[s&1] ----
        if (l == 0 && s < 20) {
            float x0 = ldin(x, ((long)(m0 + em) * 20 + s) * 2 + 0, f32);
            float x1 = ldin(x, ((long)(m0 + em) * 20 + s) * 2 + 1, f32);
            float pe = ldin(peT, s, f32) + peAg;
            float xp0 = x0 + pe, xp1 = x1 + pe;
            half8 v0, v1;
#pragma unroll
            for (int jj = 0; jj < 8; jj++) {
                float e0 = fmaf(emb0[ej + jj], xp0, fmaf(emb1[ej + jj], xp1, embb[ej + jj]));
                float e1 = fmaf(emb0[ej + 8 + jj], xp0, fmaf(emb1[ej + 8 + jj], xp1, embb[ej + 8 + jj]));
                v0[jj] = (_Float16)fmaxf(e0, 0.f);
                v1[jj] = (_Float16)fmaxf(e1, 0.f);
            }
            *(half8*)&eA[s & 1][em][ej]     = v0;   // row stride 144 B = 0 mod 16
            *(half8*)&eA[s & 1][em][ej + 8] = v1;
        }
        __syncthreads();   // single barrier per phase
    }

    // ---- epilogue 1: out = h3(19) @ outW^T + out_b ; h3(19) in buf 1 ----
    {
        const int otile = w & 3;
        const int rtb   = (w >> 2) * 2;
        half8 Ao[4];
#pragma unroll
        for (int ks = 0; ks < 4; ks++)
            Ao[ks] = *(const half8*)(ws + ((long)(528 + otile * 4 + ks)) * 512 + lane8);
        floatx4 ob;
#pragma unroll
        for (int rg = 0; rg < 4; rg++) ob[rg] = ldin(outB, otile * 16 + quad * 4 + rg, f32);
#pragma unroll
        for (int rr = 0; rr < 2; rr++) {
            const int rt = rtb + rr;
            floatx4 acc = ob;
#pragma unroll
            for (int ks = 0; ks < 4; ks++) {
                half8 b = *(const half8*)&hA[2][1][rt * 16 + nlo][ks * 32 + qk];
                acc = MFMA16(Ao[ks], b, acc);
            }
            *(floatx4*)&out[(long)(m0 + rt * 16 + nlo) * 64 + otile * 16 + quad * 4] = acc;
        }
    }

    // ---- epilogue 2: hidden finals (seq % 8 == 7), h_l(19) in buf 1 ----
    for (int idx = tid; idx < 3 * 8 * 128; idx += 512) {
        int l2 = idx >> 10, r = idx & 1023, si = r >> 7, k = r & 127;
        int sq = si * 8 + 7;
        long m = m0 + sq;
        out[1048576L + ((long)l2 * 2048 + (m >> 3)) * 128 + k] =
            (float)hA[l2][1][sq][k];
    }
}

extern "C" void kernel_launch(void* const* d_in, const int* in_sizes, int n_in,
                              void* d_out, int out_size, void* d_ws, size_t ws_size,
                              hipStream_t stream)
{
    int ix = 0, ipeA = 1, ipeT = 2, iembW = 3, iembB = 4, iWih0 = 5, iWihR = 6,
        iWhh = 7, ibih = 8, ibhh = 9, ioutW = 10, ioutB = 11;
    int f64 = -1, s64 = -1, f1152 = -1, s1152 = -1;
    for (int i = 0; i < n_in; i++) {
        int s = in_sizes[i];
        if      (s == 655360) ix = i;
        else if (s == 8)      ipeA = i;
        else if (s == 20)     ipeT = i;
        else if (s == 128)    iembW = i;
        else if (s == 24576)  iWih0 = i;
        else if (s == 98304)  iWihR = i;
        else if (s == 147456) iWhh = i;
        else if (s == 8192)   ioutW = i;
        else if (s == 64)     { if (f64 < 0) f64 = i; else s64 = i; }
        else if (s == 1152)   { if (f1152 < 0) f1152 = i; else s1152 = i; }
    }
    if (f64 >= 0)   { iembB = f64;  ioutB = (s64  >= 0 ? s64  : f64); }
    if (f1152 >= 0) { ibih = f1152; ibhh = (s1152 >= 0 ? s1152 : f1152); }

    _Float16* ws = (_Float16*)d_ws;           // 544 frags * 1KB = 557056 B
    float* out = (float*)d_out;

    hipLaunchKernelGGL(prepack_kernel, dim3(544), dim3(64), 0, stream,
                       d_in[iWhh], d_in[iWihR], d_in[iWih0], d_in[ioutW],
                       d_in[ipeT], d_in[ix], ws);
    hipLaunchKernelGGL(rnn_fused, dim3(256), dim3(512), 0, stream,
                       d_in[ix], d_in[ipeA], d_in[ipeT], d_in[iembW], d_in[iembB],
                       d_in[ibih], d_in[ibhh], d_in[ioutB], ws, out);
}

// Round 3
// 407.755 us; speedup vs baseline: 2.6599x; 2.6599x over previous
//
#include <hip/hip_runtime.h>
#include <hip/hip_bf16.h>

// ---------------------------------------------------------------------------
// Fused 3-layer GRU (B*N=16384 seqs, T=20, HS=128) for MI355X / gfx950.
// R16 = R13 (337 us proven: 12 waves, 23 phases, layer-wavefront) with:
//  (a) NO-DRAIN barrier: asm "s_waitcnt lgkmcnt(0); s_barrier" instead of
//      __syncthreads() in the phase loop. LDS cross-wave correctness needs
//      only lgkmcnt; weight loads (read-only ws) may stay in flight across
//      the barrier. Kills the per-phase vmcnt(0) drain (m97 stall mechanism).
//  (b) rolling cross-barrier prefetch: the 12 gh weight frags of ct0
//      (48 VGPR, NAMED P00..P23) are re-issued at the BOTTOM of every phase
//      and consumed at the TOP of the next -- live range = one backedge.
//      (R14/R15 lesson, measured twice: loop-spanning weight caches spill
//      to scratch regardless of naming; 1-iteration rolling ranges do not.)
//      ct0's 48 gh MFMAs then start with zero load latency; their ~900-cyc
//      burst covers the streaming of ct0-gi and all ct1 weights.
//  (c) clampless fsigm/ftanh, vectorized embedding writeback (benign).
//  (d) rotation removed (static indices required; was ~1%).
// Canary: FETCH_SIZE ~14 MB / WRITE ~28 MB. Blow-up = prefetch spilled.
// ---------------------------------------------------------------------------

typedef _Float16 half8 __attribute__((ext_vector_type(8)));
typedef _Float16 half4 __attribute__((ext_vector_type(4)));
typedef float floatx4 __attribute__((ext_vector_type(4)));

#define MFMA16(a, b, c) __builtin_amdgcn_mfma_f32_16x16x32_f16((a), (b), (c), 0, 0, 0)

static __device__ __forceinline__ float ldin(const void* p, long i, bool f32) {
    return f32 ? ((const float*)p)[i]
               : __bfloat162float(((const __hip_bfloat16*)p)[i]);
}

static __device__ __forceinline__ bool detect_f32(const void* peT, const void* x) {
    const __hip_bfloat16* a = (const __hip_bfloat16*)peT;
    const __hip_bfloat16* b = (const __hip_bfloat16*)x;
    bool weird = false;
    for (int i = 0; i < 20; i++) {
        float v = fabsf(__bfloat162float(a[i]));
        if (!(v == 0.0f || (v > 1e-8f && v < 1e8f))) weird = true;
    }
    for (int i = 0; i < 64; i++) {
        float v = fabsf(__bfloat162float(b[i]));
        if (!(v == 0.0f || (v > 1e-8f && v < 1e8f))) weird = true;
    }
    return weird;
}

// clampless: exp2(+inf)->inf, rcp(inf)->0 give correct saturation limits
static __device__ __forceinline__ float fsigm(float x) {
    float e = __builtin_amdgcn_exp2f(-1.442695041f * x);
    return __builtin_amdgcn_rcpf(1.0f + e);
}
static __device__ __forceinline__ float ftanh(float x) {
    float e = __builtin_amdgcn_exp2f(2.885390082f * x);  // exp(2x)
    return 1.0f - 2.0f * __builtin_amdgcn_rcpf(1.0f + e);
}

// ws fragment layout (each frag = 512 halfs = 64 lanes x 8): slot order
//   [0,288)   Whh   (3 layers x 96)   frag in layer: (ctile*3+g)*4+ks, ctile 0..7
//   [288,480) WihR  (2 layers x 96)   same formula
//   [480,528) Wih0  (48)              (ctile*3+g)*2+ks   (K=64)
//   [528,544) outW  (16)              otile*4+ks
__global__ __launch_bounds__(64) void prepack_kernel(
    const void* __restrict__ Whh,
    const void* __restrict__ WihR,
    const void* __restrict__ Wih0,
    const void* __restrict__ outW,
    const void* __restrict__ peT,
    const void* __restrict__ x,
    _Float16* __restrict__ ws)
{
    const bool f32 = detect_f32(peT, x);
    int fid  = blockIdx.x;
    int lane = threadIdx.x;
    int nlo = lane & 15, quad = lane >> 4;
    const void* src;
    long base;
    int row, k0, ldk;
    if (fid < 288) {
        int l = fid / 96, r = fid % 96;
        int ks = r & 3, q1 = r >> 2, g = q1 % 3, ctile = q1 / 3;
        row = g * 128 + ctile * 16 + nlo; k0 = ks * 32 + quad * 8; ldk = 128;
        src = Whh; base = (long)l * 384 * 128;
    } else if (fid < 480) {
        int f = fid - 288; int l = f / 96, r = f % 96;
        int ks = r & 3, q1 = r >> 2, g = q1 % 3, ctile = q1 / 3;
        row = g * 128 + ctile * 16 + nlo; k0 = ks * 32 + quad * 8; ldk = 128;
        src = WihR; base = (long)l * 384 * 128;
    } else if (fid < 528) {
        int r = fid - 480;
        int ks = r & 1, q1 = r >> 1, g = q1 % 3, ctile = q1 / 3;
        row = g * 128 + ctile * 16 + nlo; k0 = ks * 32 + quad * 8; ldk = 64;
        src = Wih0; base = 0;
    } else {
        int r = fid - 528; int ks = r & 3, ot = r >> 2;
        row = ot * 16 + nlo; k0 = ks * 32 + quad * 8; ldk = 128;
        src = outW; base = 0;
    }
    _Float16* d = ws + (long)fid * 512 + lane * 8;
#pragma unroll
    for (int j = 0; j < 8; j++)
        d[j] = (_Float16)ldin(src, base + (long)row * ldk + k0 + j, f32);
}

// ---- phase-body macros ----------------------------------------------------
#define MF4(WF, G) \
    acc[G][0] = MFMA16((WF), B0, acc[G][0]); \
    acc[G][1] = MFMA16((WF), B1, acc[G][1]); \
    acc[G][2] = MFMA16((WF), B2, acc[G][2]); \
    acc[G][3] = MFMA16((WF), B3, acc[G][3]);

#define BLOAD(PTR, STRIDE, KS) \
    half8 B0 = *(const half8*)((PTR) + (0*16+nlo)*(STRIDE) + (KS)*32 + qk); \
    half8 B1 = *(const half8*)((PTR) + (1*16+nlo)*(STRIDE) + (KS)*32 + qk); \
    half8 B2 = *(const half8*)((PTR) + (2*16+nlo)*(STRIDE) + (KS)*32 + qk); \
    half8 B3 = *(const half8*)((PTR) + (3*16+nlo)*(STRIDE) + (KS)*32 + qk);

// gh for ct0: weights from the cross-barrier prefetch window (zero latency)
#define GH_PF(KS) { \
    BLOAD(ghp, 136, KS) \
    MF4(P0##KS, 0) MF4(P1##KS, 1) MF4(P2##KS, 3) }

// gh for ct1: streamed from L2 (covered by ct0's MFMA burst)
#define GH_ST(KS) { \
    BLOAD(ghp, 136, KS) \
    { half8 Wf = *(const half8*)(ws + ((long)(lb96 + (c8*3+0)*4 + (KS)))*512 + lane8); MF4(Wf, 0) } \
    { half8 Wf = *(const half8*)(ws + ((long)(lb96 + (c8*3+1)*4 + (KS)))*512 + lane8); MF4(Wf, 1) } \
    { half8 Wf = *(const half8*)(ws + ((long)(lb96 + (c8*3+2)*4 + (KS)))*512 + lane8); MF4(Wf, 3) } }

#define ACC_INIT \
    floatx4 acc[4][4]; \
    _Pragma("unroll") for (int g = 0; g < 4; g++) { \
        floatx4 b = *(const floatx4*)&biasS[(l*4+g)*128 + c4]; \
        _Pragma("unroll") for (int rt = 0; rt < 4; rt++) acc[g][rt] = b; }

#define GI_STREAM \
    for (int ks = 0; ks < KGI; ks++) { \
        half8 B0 = *(const half8*)(inBase + (0*16+nlo)*inStride + ks*32 + qk); \
        half8 B1 = *(const half8*)(inBase + (1*16+nlo)*inStride + ks*32 + qk); \
        half8 B2 = *(const half8*)(inBase + (2*16+nlo)*inStride + ks*32 + qk); \
        half8 B3 = *(const half8*)(inBase + (3*16+nlo)*inStride + ks*32 + qk); \
        _Pragma("unroll") for (int g = 0; g < 3; g++) { \
            long f = (l == 0) ? (long)(480 + (c8*3+g)*2 + ks) \
                              : (long)(288 + (l-1)*96 + (c8*3+g)*4 + ks); \
            half8 Uf = *(const half8*)(ws + f*512 + lane8); \
            MF4(Uf, g) } }

#define NONLIN \
    _Pragma("unroll") for (int rt = 0; rt < 4; rt++) { \
        half4 ho = *(const half4*)&hA[l][p][rt*16+nlo][c4]; \
        half4 hn; \
        _Pragma("unroll") for (int rg = 0; rg < 4; rg++) { \
            float r = fsigm(acc[0][rt][rg]); \
            float z = fsigm(acc[1][rt][rg]); \
            float n = ftanh(acc[2][rt][rg] + r * acc[3][rt][rg]); \
            hn[rg] = (_Float16)(n + z * ((float)ho[rg] - n)); } \
        *(half4*)&hA[l][q][rt*16+nlo][c4] = hn; }

#define PFA(G, KS) (*(const half8*)(ws + ((long)(lb96 + ((W*2)*3+(G))*4 + (KS)))*512 + lane8))
#define PF_ISSUE \
    P00 = PFA(0,0); P01 = PFA(0,1); P02 = PFA(0,2); P03 = PFA(0,3); \
    P10 = PFA(1,0); P11 = PFA(1,1); P12 = PFA(1,2); P13 = PFA(1,3); \
    P20 = PFA(2,0); P21 = PFA(2,1); P22 = PFA(2,2); P23 = PFA(2,3);

__global__ __launch_bounds__(768, 3) void rnn_fused(
    const void* __restrict__ x,
    const void* __restrict__ peA,
    const void* __restrict__ peT,
    const void* __restrict__ embW,
    const void* __restrict__ embB,
    const void* __restrict__ bih,
    const void* __restrict__ bhh,
    const void* __restrict__ outB,
    const _Float16* __restrict__ ws,
    float* __restrict__ out)
{
    __shared__ __align__(16) _Float16 hA[3][2][64][136];
    __shared__ __align__(16) _Float16 eA[2][64][72];
    __shared__ float emb0[64], emb1[64], embb[64];
    __shared__ float biasS[1536];   // [l][R,Z,Ni,Nh][128]

    const bool f32 = detect_f32(peT, x);

    const int tid  = threadIdx.x;
    const int w    = tid >> 6;      // 0..11
    const int lane = tid & 63;
    const int nlo  = lane & 15;
    const int quad = lane >> 4;
    const int qk   = quad * 8;
    const int lane8 = lane * 8;
    const int m0   = blockIdx.x * 64;
    const int l    = w >> 2;        // 0..2
    const int W    = w & 3;         // quarter: ctiles W*2, W*2+1
    const int lb96 = l * 96;        // Whh frag base for this layer

    for (int i = tid; i < 3 * 2 * 64 * 136; i += 768)
        (&hA[0][0][0][0])[i] = (_Float16)0.f;
    if (tid < 64) {
        emb0[tid] = ldin(embW, tid * 2 + 0, f32);
        emb1[tid] = ldin(embW, tid * 2 + 1, f32);
        embb[tid] = ldin(embB, tid, f32);
    }
    for (int idx = tid; idx < 1536; idx += 768) {
        int ll = idx >> 9, r = idx & 511, g = r >> 7, c = r & 127;
        float v;
        if      (g == 0) v = ldin(bih, ll * 384 + c, f32)       + ldin(bhh, ll * 384 + c, f32);
        else if (g == 1) v = ldin(bih, ll * 384 + 128 + c, f32) + ldin(bhh, ll * 384 + 128 + c, f32);
        else if (g == 2) v = ldin(bih, ll * 384 + 256 + c, f32);
        else             v = ldin(bhh, ll * 384 + 256 + c, f32);
        biasS[idx] = v;
    }

    const int em = tid >> 2;          // embedding seq (layer-0 waves: tid<256)
    const int ej = (tid & 3) * 16;    // embedding col base
    const float peAg = ldin(peA, ((m0 + em) & 7), f32);

    // ---- rolling prefetch window: gh weights of ct0 (12 frags, 48 VGPR) ----
    half8 P00, P01, P02, P03, P10, P11, P12, P13, P20, P21, P22, P23;
    PF_ISSUE                     // prime for phase 0

    __syncthreads();

#pragma unroll 1
    for (int s = 0; s < 23; s++) {
        const int t = s - 1 - l;
        if (t >= 0 && t < 20) {
            const int p = (t + 1) & 1;
            const int q = t & 1;
            const int KGI = (l == 0) ? 2 : 4;
            const _Float16* inBase = (l == 0) ? &eA[t & 1][0][0]
                                              : &hA[l - 1][t & 1][0][0];
            const int inStride = (l == 0) ? 72 : 136;
            const _Float16* ghp = &hA[l][p][0][0];

            {   // ---- ct0: gh from prefetch window ----
                const int c8 = W * 2;
                const int c4 = c8 * 16 + quad * 4;
                ACC_INIT
                GH_PF(0) GH_PF(1) GH_PF(2) GH_PF(3)
                GI_STREAM
                NONLIN
            }
            {   // ---- ct1: gh streamed ----
                const int c8 = W * 2 + 1;
                const int c4 = c8 * 16 + quad * 4;
                ACC_INIT
                GH_ST(0) GH_ST(1) GH_ST(2) GH_ST(3)
                GI_STREAM
                NONLIN
            }
        }
        // ---- embedding fused into layer-0 waves: e(t=s) -> eA[s&1] ----
        if (l == 0 && s < 20) {
            float x0 = ldin(x, ((long)(m0 + em) * 20 + s) * 2 + 0, f32);
            float x1 = ldin(x, ((long)(m0 + em) * 20 + s) * 2 + 1, f32);
            float pe = ldin(peT, s, f32) + peAg;
            float xp0 = x0 + pe, xp1 = x1 + pe;
            half8 v0, v1;
#pragma unroll
            for (int jj = 0; jj < 8; jj++) {
                float e0 = fmaf(emb0[ej + jj], xp0, fmaf(emb1[ej + jj], xp1, embb[ej + jj]));
                float e1 = fmaf(emb0[ej + 8 + jj], xp0, fmaf(emb1[ej + 8 + jj], xp1, embb[ej + 8 + jj]));
                v0[jj] = (_Float16)fmaxf(e0, 0.f);
                v1[jj] = (_Float16)fmaxf(e1, 0.f);
            }
            *(half8*)&eA[s & 1][em][ej]     = v0;   // row stride 144 B = 0 mod 16
            *(half8*)&eA[s & 1][em][ej + 8] = v1;
        }

        // re-issue the prefetch window for the next phase (same addresses,
        // fresh defs -> live range = one backedge; loads stay in flight
        // across the no-drain barrier below)
        PF_ISSUE

        // no-drain barrier: LDS ordering only; vmcnt NOT drained
        asm volatile("s_waitcnt lgkmcnt(0)\n\ts_barrier" ::: "memory");
    }

    // ---- epilogue 1: out = h3(19) @ outW^T + out_b ; h3(19) in buf 1 ----
    if (w < 8) {
        const int otile = w & 3;
        const int rtb   = (w >> 2) * 2;
        half8 Ao[4];
#pragma unroll
        for (int ks = 0; ks < 4; ks++)
            Ao[ks] = *(const half8*)(ws + ((long)(528 + otile * 4 + ks)) * 512 + lane8);
        floatx4 ob;
#pragma unroll
        for (int rg = 0; rg < 4; rg++) ob[rg] = ldin(outB, otile * 16 + quad * 4 + rg, f32);
#pragma unroll
        for (int rr = 0; rr < 2; rr++) {
            const int rt = rtb + rr;
            floatx4 acc = ob;
#pragma unroll
            for (int ks = 0; ks < 4; ks++) {
                half8 b = *(const half8*)&hA[2][1][rt * 16 + nlo][ks * 32 + qk];
                acc = MFMA16(Ao[ks], b, acc);
            }
            *(floatx4*)&out[(long)(m0 + rt * 16 + nlo) * 64 + otile * 16 + quad * 4] = acc;
        }
    }

    // ---- epilogue 2: hidden finals (seq % 8 == 7), h_l(19) in buf 1 ----
    for (int idx = tid; idx < 3 * 8 * 128; idx += 768) {
        int l2 = idx >> 10, r = idx & 1023, si = r >> 7, k = r & 127;
        int sq = si * 8 + 7;
        long m = m0 + sq;
        out[1048576L + ((long)l2 * 2048 + (m >> 3)) * 128 + k] =
            (float)hA[l2][1][sq][k];
    }
}

extern "C" void kernel_launch(void* const* d_in, const int* in_sizes, int n_in,
                              void* d_out, int out_size, void* d_ws, size_t ws_size,
                              hipStream_t stream)
{
    int ix = 0, ipeA = 1, ipeT = 2, iembW = 3, iembB = 4, iWih0 = 5, iWihR = 6,
        iWhh = 7, ibih = 8, ibhh = 9, ioutW = 10, ioutB = 11;
    int f64 = -1, s64 = -1, f1152 = -1, s1152 = -1;
    for (int i = 0; i < n_in; i++) {
        int s = in_sizes[i];
        if      (s == 655360) ix = i;
        else if (s == 8)      ipeA = i;
        else if (s == 20)     ipeT = i;
        else if (s == 128)    iembW = i;
        else if (s == 24576)  iWih0 = i;
        else if (s == 98304)  iWihR = i;
        else if (s == 147456) iWhh = i;
        else if (s == 8192)   ioutW = i;
        else if (s == 64)     { if (f64 < 0) f64 = i; else s64 = i; }
        else if (s == 1152)   { if (f1152 < 0) f1152 = i; else s1152 = i; }
    }
    if (f64 >= 0)   { iembB = f64;  ioutB = (s64  >= 0 ? s64  : f64); }
    if (f1152 >= 0) { ibih = f1152; ibhh = (s1152 >= 0 ? s1152 : f1152); }

    _Float16* ws = (_Float16*)d_ws;           // 544 frags * 1KB = 557056 B
    float* out = (float*)d_out;

    hipLaunchKernelGGL(prepack_kernel, dim3(544), dim3(64), 0, stream,
                       d_in[iWhh], d_in[iWihR], d_in[iWih0], d_in[ioutW],
                       d_in[ipeT], d_in[ix], ws);
    hipLaunchKernelGGL(rnn_fused, dim3(256), dim3(768), 0, stream,
                       d_in[ix], d_in[ipeA], d_in[ipeT], d_in[iembW], d_in[iembB],
                       d_in[ibih], d_in[ibhh], d_in[ioutB], ws, out);
}